// Round 15
// baseline (79.335 us; speedup 1.0000x reference)
//
#include <hip/hip_runtime.h>
#include <math.h>

#define NB 2
#define NL 256
#define NH 768
#define NI 1536
#define NM (NB * NL)   // 512

typedef __attribute__((ext_vector_type(8))) short bf16x8;
typedef __attribute__((ext_vector_type(4))) float f32x4;

#if __has_builtin(__builtin_amdgcn_exp2f)
#define FAST_EXP2(x) __builtin_amdgcn_exp2f(x)
#else
#define FAST_EXP2(x) exp2f(x)
#endif
#if __has_builtin(__builtin_amdgcn_rcpf)
#define FAST_RCP(x) __builtin_amdgcn_rcpf(x)
#else
#define FAST_RCP(x) (1.0f / (x))
#endif

// fp32 -> bf16 round-to-nearest-even, packed pair
__device__ __forceinline__ unsigned short f2bf(float f) {
  unsigned int u = __builtin_bit_cast(unsigned int, f);
  u += 0x7FFFu + ((u >> 16) & 1u);
  return (unsigned short)(u >> 16);
}
__device__ __forceinline__ unsigned int pack2(float lo, float hi) {
  return (unsigned int)f2bf(lo) | ((unsigned int)f2bf(hi) << 16);
}

// ---------------------------------------------------------------------------
// Kernel 1: start/end logits. One block per row m, 256 threads.
// ---------------------------------------------------------------------------
__global__ __launch_bounds__(256) void logits_kernel(
    const float* __restrict__ hs,
    const float* __restrict__ sw, const float* __restrict__ sb,
    const float* __restrict__ ew, const float* __restrict__ eb,
    float* __restrict__ out) {
  int m = blockIdx.x;
  int tid = threadIdx.x;
  const float* row = hs + (size_t)m * NH;
  float accs = 0.f, acce = 0.f;
  for (int h = tid; h < NH; h += 256) {
    float v = row[h];
    accs = fmaf(v, sw[h], accs);
    acce = fmaf(v, ew[h], acce);
  }
  for (int off = 32; off > 0; off >>= 1) {
    accs += __shfl_down(accs, off, 64);
    acce += __shfl_down(acce, off, 64);
  }
  __shared__ float s_s[4], s_e[4];
  int wid = tid >> 6;
  if ((tid & 63) == 0) { s_s[wid] = accs; s_e[wid] = acce; }
  __syncthreads();
  if (tid == 0) {
    float ts = s_s[0] + s_s[1] + s_s[2] + s_s[3];
    float te = s_e[0] + s_e[1] + s_e[2] + s_e[3];
    out[m]      = ts + sb[0];
    out[NM + m] = te + eb[0];
  }
}

// ---------------------------------------------------------------------------
// Kernel 2: bf16 MFMA GEMM v2 (unchanged from R13 — 8 waves, pipelined).
// mode = blockIdx.z: 0 -> aOut[m][n] (+b1);  1 -> cT[b][i=n][t=m]
// ---------------------------------------------------------------------------
__global__ __launch_bounds__(512) void gemm_mfma(
    const float* __restrict__ hs, const float* __restrict__ w1,
    const float* __restrict__ b1, float* __restrict__ aOut,
    float* __restrict__ cT) {
  constexpr int BM = 64, BN = 96, BK = 32;
  __shared__ short A_lds[BM * BK];   // [64][32] swizzled, 4 KB
  __shared__ short B_lds[BN * BK];   // [96][32] swizzled, 6 KB

  const int mode = blockIdx.z;
  const float* __restrict__ W = w1 + (size_t)mode * NH * NI;
  const int m0 = blockIdx.x * BM;
  const int n0 = blockIdx.y * BN;
  const int tid = threadIdx.x;
  const int lane = tid & 63;
  const int wid = tid >> 6;          // 0..7
  const int wr = wid >> 1;           // 0..3  (m quarter, 16 rows)
  const int wc = wid & 1;            // 0..1  (n half, 48 cols)

  const int ar  = tid >> 3;          // A row 0..63
  const int ac  = (tid & 7) * 4;     // A k-offset {0,4,...,28}, float4
  const int bkq = (tid >> 5) * 2;    // B k-offset {0,2,...,30}, 2 rows
  const int bnl = tid & 31;          // B n-lane (n = bnl + nn*32, nn<3)

  f32x4 acc[3] = {};

  float4 av = *reinterpret_cast<const float4*>(hs + (size_t)(m0 + ar) * NH + ac);
  float bv[2][3];
#pragma unroll
  for (int j = 0; j < 2; ++j) {
    const float* pb = W + (size_t)(bkq + j) * NI + n0 + bnl;
#pragma unroll
    for (int nn = 0; nn < 3; ++nn) bv[j][nn] = pb[nn * 32];
  }

  for (int k0 = 0; k0 < NH; k0 += BK) {
    __syncthreads();
    {
      uint2 v;
      v.x = pack2(av.x, av.y);
      v.y = pack2(av.z, av.w);
      const int off = ar * 64 + ((((ac >> 3) & 3) ^ (ar & 3)) << 4) + ((ac & 4) << 1);
      *reinterpret_cast<uint2*>(reinterpret_cast<char*>(A_lds) + off) = v;
    }
#pragma unroll
    for (int nn = 0; nn < 3; ++nn) {
      const int n = bnl + nn * 32;
      unsigned int v = pack2(bv[0][nn], bv[1][nn]);
      const int off = n * 64 + (((bkq >> 3) ^ (n & 3)) << 4) + ((bkq * 2) & 12);
      *reinterpret_cast<unsigned int*>(reinterpret_cast<char*>(B_lds) + off) = v;
    }
    __syncthreads();
    const int kn = k0 + BK;
    if (kn < NH) {
      av = *reinterpret_cast<const float4*>(hs + (size_t)(m0 + ar) * NH + kn + ac);
#pragma unroll
      for (int j = 0; j < 2; ++j) {
        const float* pb = W + (size_t)(kn + bkq + j) * NI + n0 + bnl;
#pragma unroll
        for (int nn = 0; nn < 3; ++nn) bv[j][nn] = pb[nn * 32];
      }
    }
    const int lr = lane & 15, ls = lane >> 4;
    bf16x8 af, bf[3];
    {
      const int row = wr * 16 + lr;
      const int off = row * 64 + ((ls ^ (row & 3)) << 4);
      af = *reinterpret_cast<const bf16x8*>(reinterpret_cast<const char*>(A_lds) + off);
    }
#pragma unroll
    for (int nt = 0; nt < 3; ++nt) {
      const int nrow = wc * 48 + nt * 16 + lr;
      const int off = nrow * 64 + ((ls ^ (nrow & 3)) << 4);
      bf[nt] = *reinterpret_cast<const bf16x8*>(reinterpret_cast<const char*>(B_lds) + off);
    }
#pragma unroll
    for (int nt = 0; nt < 3; ++nt)
      acc[nt] = __builtin_amdgcn_mfma_f32_16x16x32_bf16(af, bf[nt], acc[nt], 0, 0, 0);
  }

  const int lr = lane & 15, lq = lane >> 4;
  if (mode == 0) {
    const int mb = m0 + wr * 16 + lq * 4;
#pragma unroll
    for (int nt = 0; nt < 3; ++nt) {
      const int n = n0 + wc * 48 + nt * 16 + lr;
      const float bias = b1[n];
#pragma unroll
      for (int r = 0; r < 4; ++r)
        aOut[(size_t)(mb + r) * NI + n] = acc[nt][r] + bias;
    }
  } else {
    const int b = m0 >> 8;
    const int tb = (m0 & (NL - 1)) + wr * 16 + lq * 4;
#pragma unroll
    for (int nt = 0; nt < 3; ++nt) {
      const int i = n0 + wc * 48 + nt * 16 + lr;
      *reinterpret_cast<f32x4*>(cT + (size_t)b * NI * NL + (size_t)i * NL + tb) = acc[nt];
    }
  }
}

// ---------------------------------------------------------------------------
// Kernel 3: span logits v11 — quick gelu (R14) + 2-deep cv prefetch.
// Loads for i+2,i+3 issue BEFORE computing i,i+1 (latency hidden within
// wave, on top of TLP). 2-i groups keep live cv regs at 4 x float4 — same
// as R14's batch-of-4, so VGPR should stay ~60 (no spill at cap 256).
// Everything else identical to R14 (57.5 µs): quick gelu x*sigmoid(1.702x),
// 4-wide batched rcp, grid 2048 = 256 s-pairs x 8 t-eighths, 256 thr.
// ---------------------------------------------------------------------------
__global__ __launch_bounds__(256, 2) void span_kernel(
    const float* __restrict__ aRow,   // [M][I], b1 folded
    const float* __restrict__ cT,     // [B][I][L]
    const float* __restrict__ w2,
    const float* __restrict__ b2,
    float* __restrict__ out) {
  const int blk = blockIdx.x;          // 0..2047
  const int sg  = blk >> 3;            // s-pair 0..255
  const int te  = blk & 7;             // t-eighth
  const int s0  = sg * 2;
  const int b   = s0 >> 8;
  const int tbase = te * 32;
  const int tid = threadIdx.x;
  const int t4  = tid & 7;             // 8 lanes x 4 t = 32 t
  const int q   = tid >> 3;            // 0..31, 48-i chunk each
  const int lane = tid & 63;
  const int w    = tid >> 6;           // wave 0..3

  __shared__ float4 aw[NI + 32];       // (a0, a1, w2, 0), skew i+i/48: 24.5 KB
  __shared__ float4 red[4][2][8];      // 1 KB

  const float* a0p = aRow + (size_t)s0 * NI;
  const float* a1p = a0p + NI;
  for (int i = tid; i < NI; i += 256)
    aw[i + i / 48] = make_float4(a0p[i], a1p[i], w2[i], 0.f);
  __syncthreads();

  const float* cb = cT + (size_t)b * NI * NL + (size_t)(q * 48) * NL + tbase + t4 * 4;
  const float4* awq = aw + q * 49;

  f32x4 acc0 = {0.f, 0.f, 0.f, 0.f};
  f32x4 acc1 = {0.f, 0.f, 0.f, 0.f};
  const float KQ = -2.4554669f;   // -1.702 * log2(e)

// one s across 4 t: quick-gelu with 4-wide batched reciprocal
#define GEL4(ACC, A, CV, WH)                             \
  {                                                      \
    float x0 = (A) + (CV).x, x1 = (A) + (CV).y;          \
    float x2 = (A) + (CV).z, x3 = (A) + (CV).w;          \
    float d0 = FAST_EXP2(KQ * x0) + 1.f;                 \
    float d1 = FAST_EXP2(KQ * x1) + 1.f;                 \
    float d2 = FAST_EXP2(KQ * x2) + 1.f;                 \
    float d3 = FAST_EXP2(KQ * x3) + 1.f;                 \
    float m01 = d0 * d1, m23 = d2 * d3;                  \
    float r = FAST_RCP(m01 * m23);                       \
    float r01 = r * m23, r23 = r * m01;                  \
    ACC[0] = fmaf(x0 * (WH), r01 * d1, ACC[0]);          \
    ACC[1] = fmaf(x1 * (WH), r01 * d0, ACC[1]);          \
    ACC[2] = fmaf(x2 * (WH), r23 * d3, ACC[2]);          \
    ACC[3] = fmaf(x3 * (WH), r23 * d2, ACC[3]);          \
  }

  // 2-deep software pipeline over 48 i (2-i groups)
  float4 c0 = *reinterpret_cast<const float4*>(cb);
  float4 c1 = *reinterpret_cast<const float4*>(cb + NL);
#pragma unroll 4
  for (int ii = 0; ii < 48; ii += 2) {
    float4 n0, n1;
    if (ii + 2 < 48) {
      n0 = *reinterpret_cast<const float4*>(cb + 2 * NL);
      n1 = *reinterpret_cast<const float4*>(cb + 3 * NL);
    }
    float4 awA = awq[ii + 0];
    float4 awB = awq[ii + 1];
    GEL4(acc0, awA.x, c0, awA.z)  GEL4(acc1, awA.y, c0, awA.z)
    GEL4(acc0, awB.x, c1, awB.z)  GEL4(acc1, awB.y, c1, awB.z)
    c0 = n0; c1 = n1;
    cb += 2 * NL;
  }
#undef GEL4

  // fold lane bits 3,4,5 (q-groups within wave)
#pragma unroll
  for (int k = 0; k < 4; ++k) {
    acc0[k] += __shfl_xor(acc0[k], 8, 64);
    acc0[k] += __shfl_xor(acc0[k], 16, 64);
    acc0[k] += __shfl_xor(acc0[k], 32, 64);
    acc1[k] += __shfl_xor(acc1[k], 8, 64);
    acc1[k] += __shfl_xor(acc1[k], 16, 64);
    acc1[k] += __shfl_xor(acc1[k], 32, 64);
  }
  if (lane < 8) {
    red[w][0][lane] = make_float4(acc0[0], acc0[1], acc0[2], acc0[3]);
    red[w][1][lane] = make_float4(acc1[0], acc1[1], acc1[2], acc1[3]);
  }
  __syncthreads();
  if (tid < 16) {
    const int s = tid >> 3;
    const int tt = tid & 7;
    float4 v0 = red[0][s][tt];
    float4 v1 = red[1][s][tt];
    float4 v2 = red[2][s][tt];
    float4 v3 = red[3][s][tt];
    const float bb = b2[0];
    float4 o;
    o.x = (v0.x + v1.x) + (v2.x + v3.x) + bb;
    o.y = (v0.y + v1.y) + (v2.y + v3.y) + bb;
    o.z = (v0.z + v1.z) + (v2.z + v3.z) + bb;
    o.w = (v0.w + v1.w) + (v2.w + v3.w) + bb;
    *reinterpret_cast<float4*>(out + 2 * NM + (size_t)(s0 + s) * NL + tbase + tt * 4) = o;
  }
}

// ---------------------------------------------------------------------------
extern "C" void kernel_launch(void* const* d_in, const int* in_sizes, int n_in,
                              void* d_out, int out_size, void* d_ws, size_t ws_size,
                              hipStream_t stream) {
  const float* hs = (const float*)d_in[0];
  const float* sw = (const float*)d_in[1];
  const float* sb = (const float*)d_in[2];
  const float* ew = (const float*)d_in[3];
  const float* eb = (const float*)d_in[4];
  const float* w1 = (const float*)d_in[5];
  const float* b1 = (const float*)d_in[6];
  const float* w2 = (const float*)d_in[7];
  const float* b2 = (const float*)d_in[8];
  float* out = (float*)d_out;

  float* a  = (float*)d_ws;                           // M*I floats = 3 MB
  float* cT = (float*)d_ws + (size_t)NM * NI;         // B*I*L floats = 3 MB

  logits_kernel<<<NM, 256, 0, stream>>>(hs, sw, sb, ew, eb, out);

  dim3 ggrid(NM / 64, NI / 96, 2);
  gemm_mfma<<<ggrid, 512, 0, stream>>>(hs, w1, b1, a, cT);

  span_kernel<<<2048, 256, 0, stream>>>(a, cT, w2, b2, out);
}

// Round 16
// 76.418 us; speedup vs baseline: 1.0382x; 1.0382x over previous
//
#include <hip/hip_runtime.h>
#include <math.h>

#define NB 2
#define NL 256
#define NH 768
#define NI 1536
#define NM (NB * NL)   // 512

typedef __attribute__((ext_vector_type(8))) short bf16x8;
typedef __attribute__((ext_vector_type(4))) float f32x4;

#if __has_builtin(__builtin_amdgcn_exp2f)
#define FAST_EXP2(x) __builtin_amdgcn_exp2f(x)
#else
#define FAST_EXP2(x) exp2f(x)
#endif
#if __has_builtin(__builtin_amdgcn_rcpf)
#define FAST_RCP(x) __builtin_amdgcn_rcpf(x)
#else
#define FAST_RCP(x) (1.0f / (x))
#endif

#define KQ (-2.4554669f)   // -1.702 * log2(e)  (quick-gelu exponent)

// fp32 -> bf16 round-to-nearest-even, packed pair
__device__ __forceinline__ unsigned short f2bf(float f) {
  unsigned int u = __builtin_bit_cast(unsigned int, f);
  u += 0x7FFFu + ((u >> 16) & 1u);
  return (unsigned short)(u >> 16);
}
__device__ __forceinline__ unsigned int pack2(float lo, float hi) {
  return (unsigned int)f2bf(lo) | ((unsigned int)f2bf(hi) << 16);
}

// ---------------------------------------------------------------------------
// Kernel 1: start/end logits. One block per row m, 256 threads.
// ---------------------------------------------------------------------------
__global__ __launch_bounds__(256) void logits_kernel(
    const float* __restrict__ hs,
    const float* __restrict__ sw, const float* __restrict__ sb,
    const float* __restrict__ ew, const float* __restrict__ eb,
    float* __restrict__ out) {
  int m = blockIdx.x;
  int tid = threadIdx.x;
  const float* row = hs + (size_t)m * NH;
  float accs = 0.f, acce = 0.f;
  for (int h = tid; h < NH; h += 256) {
    float v = row[h];
    accs = fmaf(v, sw[h], accs);
    acce = fmaf(v, ew[h], acce);
  }
  for (int off = 32; off > 0; off >>= 1) {
    accs += __shfl_down(accs, off, 64);
    acce += __shfl_down(acce, off, 64);
  }
  __shared__ float s_s[4], s_e[4];
  int wid = tid >> 6;
  if ((tid & 63) == 0) { s_s[wid] = accs; s_e[wid] = acce; }
  __syncthreads();
  if (tid == 0) {
    float ts = s_s[0] + s_s[1] + s_s[2] + s_s[3];
    float te = s_e[0] + s_e[1] + s_e[2] + s_e[3];
    out[m]      = ts + sb[0];
    out[NM + m] = te + eb[0];
  }
}

// ---------------------------------------------------------------------------
// Kernel 2: bf16 MFMA GEMM (R13 structure; mode-1 epilogue now ALSO emits
// E_c = exp2(KQ*c), interleaved: cE[b][i][t] = (c, E_c) float2.
// mode = blockIdx.z: 0 -> aOut[m][n] (+b1);  1 -> cE interleaved
// ---------------------------------------------------------------------------
__global__ __launch_bounds__(512) void gemm_mfma(
    const float* __restrict__ hs, const float* __restrict__ w1,
    const float* __restrict__ b1, float* __restrict__ aOut,
    float* __restrict__ cE) {
  constexpr int BM = 64, BN = 96, BK = 32;
  __shared__ short A_lds[BM * BK];   // [64][32] swizzled, 4 KB
  __shared__ short B_lds[BN * BK];   // [96][32] swizzled, 6 KB

  const int mode = blockIdx.z;
  const float* __restrict__ W = w1 + (size_t)mode * NH * NI;
  const int m0 = blockIdx.x * BM;
  const int n0 = blockIdx.y * BN;
  const int tid = threadIdx.x;
  const int lane = tid & 63;
  const int wid = tid >> 6;          // 0..7
  const int wr = wid >> 1;           // 0..3  (m quarter, 16 rows)
  const int wc = wid & 1;            // 0..1  (n half, 48 cols)

  const int ar  = tid >> 3;          // A row 0..63
  const int ac  = (tid & 7) * 4;     // A k-offset, float4
  const int bkq = (tid >> 5) * 2;    // B k-offset, 2 rows
  const int bnl = tid & 31;          // B n-lane

  f32x4 acc[3] = {};

  float4 av = *reinterpret_cast<const float4*>(hs + (size_t)(m0 + ar) * NH + ac);
  float bv[2][3];
#pragma unroll
  for (int j = 0; j < 2; ++j) {
    const float* pb = W + (size_t)(bkq + j) * NI + n0 + bnl;
#pragma unroll
    for (int nn = 0; nn < 3; ++nn) bv[j][nn] = pb[nn * 32];
  }

  for (int k0 = 0; k0 < NH; k0 += BK) {
    __syncthreads();
    {
      uint2 v;
      v.x = pack2(av.x, av.y);
      v.y = pack2(av.z, av.w);
      const int off = ar * 64 + ((((ac >> 3) & 3) ^ (ar & 3)) << 4) + ((ac & 4) << 1);
      *reinterpret_cast<uint2*>(reinterpret_cast<char*>(A_lds) + off) = v;
    }
#pragma unroll
    for (int nn = 0; nn < 3; ++nn) {
      const int n = bnl + nn * 32;
      unsigned int v = pack2(bv[0][nn], bv[1][nn]);
      const int off = n * 64 + (((bkq >> 3) ^ (n & 3)) << 4) + ((bkq * 2) & 12);
      *reinterpret_cast<unsigned int*>(reinterpret_cast<char*>(B_lds) + off) = v;
    }
    __syncthreads();
    const int kn = k0 + BK;
    if (kn < NH) {
      av = *reinterpret_cast<const float4*>(hs + (size_t)(m0 + ar) * NH + kn + ac);
#pragma unroll
      for (int j = 0; j < 2; ++j) {
        const float* pb = W + (size_t)(kn + bkq + j) * NI + n0 + bnl;
#pragma unroll
        for (int nn = 0; nn < 3; ++nn) bv[j][nn] = pb[nn * 32];
      }
    }
    const int lr = lane & 15, ls = lane >> 4;
    bf16x8 af, bf[3];
    {
      const int row = wr * 16 + lr;
      const int off = row * 64 + ((ls ^ (row & 3)) << 4);
      af = *reinterpret_cast<const bf16x8*>(reinterpret_cast<const char*>(A_lds) + off);
    }
#pragma unroll
    for (int nt = 0; nt < 3; ++nt) {
      const int nrow = wc * 48 + nt * 16 + lr;
      const int off = nrow * 64 + ((ls ^ (nrow & 3)) << 4);
      bf[nt] = *reinterpret_cast<const bf16x8*>(reinterpret_cast<const char*>(B_lds) + off);
    }
#pragma unroll
    for (int nt = 0; nt < 3; ++nt)
      acc[nt] = __builtin_amdgcn_mfma_f32_16x16x32_bf16(af, bf[nt], acc[nt], 0, 0, 0);
  }

  const int lr = lane & 15, lq = lane >> 4;
  if (mode == 0) {
    const int mb = m0 + wr * 16 + lq * 4;
#pragma unroll
    for (int nt = 0; nt < 3; ++nt) {
      const int n = n0 + wc * 48 + nt * 16 + lr;
      const float bias = b1[n];
#pragma unroll
      for (int r = 0; r < 4; ++r)
        aOut[(size_t)(mb + r) * NI + n] = acc[nt][r] + bias;
    }
  } else {
    // interleaved (c, exp2(KQ*c)) per t; acc[nt][r] is t = tb + r
    const int b = m0 >> 8;
    const int tb = (m0 & (NL - 1)) + wr * 16 + lq * 4;
#pragma unroll
    for (int nt = 0; nt < 3; ++nt) {
      const int i = n0 + wc * 48 + nt * 16 + lr;
      float* dst = cE + (((size_t)b * NI + i) * NL + tb) * 2;
      f32x4 v = acc[nt];
      float e0 = FAST_EXP2(KQ * v[0]);
      float e1 = FAST_EXP2(KQ * v[1]);
      float e2 = FAST_EXP2(KQ * v[2]);
      float e3 = FAST_EXP2(KQ * v[3]);
      float4 lo = make_float4(v[0], e0, v[1], e1);
      float4 hi = make_float4(v[2], e2, v[3], e3);
      *reinterpret_cast<float4*>(dst)     = lo;
      *reinterpret_cast<float4*>(dst + 4) = hi;
    }
  }
}

// ---------------------------------------------------------------------------
// Kernel 3: span logits v12 — FACTORIZED EXPONENTIAL (transcendental-free
// inner loop). exp2(KQ*(a+c)) = exp2(KQ*a)*exp2(KQ*c); E_c precomputed in
// GEMM epilogue, E_a at LDS-staging. Inner loop per 4 elems (2s x 2t):
//   x = a+c (4 add); d = fma(Ea,Ec,1) (4 fma); batched rcp (9 mul + 1 rcp);
//   acc = fma(x*w, 1/d, acc) (4 mul + 4 fma)  -> 25 VALU + 1/4 rcp per elem4.
// Grid 2048 = 256 s-pairs x 8 t-eighths, 256 thr. Lane: t16 = tid&15 covers
// 2 t (one float4 = (c0,E0,c1,E1)); q = tid>>4 covers 96 i.
// ---------------------------------------------------------------------------
__global__ __launch_bounds__(256, 2) void span_kernel(
    const float* __restrict__ aRow,   // [M][I], b1 folded
    const float* __restrict__ cE,     // [B][I][L] float2 interleaved (c, Ec)
    const float* __restrict__ w2,
    const float* __restrict__ b2,
    float* __restrict__ out) {
  const int blk = blockIdx.x;          // 0..2047
  const int sg  = blk >> 3;            // s-pair 0..255
  const int te  = blk & 7;             // t-eighth
  const int s0  = sg * 2;
  const int b   = s0 >> 8;
  const int tbase = te * 32;
  const int tid = threadIdx.x;
  const int t16 = tid & 15;            // 16 lanes x 2 t = 32 t
  const int q   = tid >> 4;            // 0..15, 96-i chunk each
  const int lane = tid & 63;
  const int w    = tid >> 6;           // wave 0..3

  __shared__ float4 aw4[NI + 16];      // (a0, a1, Ea0, Ea1), skew i+i/96: 24.8 KB
  __shared__ float  wls[NI + 16];      // w2, skewed: 6.2 KB
  __shared__ float4 red[4][16];        // 1 KB

  const float* a0p = aRow + (size_t)s0 * NI;
  const float* a1p = a0p + NI;
  for (int i = tid; i < NI; i += 256) {
    float a0 = a0p[i], a1 = a1p[i];
    aw4[i + i / 96] = make_float4(a0, a1, FAST_EXP2(KQ * a0), FAST_EXP2(KQ * a1));
    wls[i + i / 96] = w2[i];
  }
  __syncthreads();

  const float* cb = cE + (((size_t)b * NI + q * 96) * NL + tbase + t16 * 2) * 2;
  const float4* awq = aw4 + q * 97;
  const float* wq = wls + q * 97;

  f32x4 acc = {0.f, 0.f, 0.f, 0.f};    // [s0t0, s0t1, s1t0, s1t1]

#pragma unroll 4
  for (int ii = 0; ii < 96; ++ii) {
    float4 cv = *reinterpret_cast<const float4*>(cb);   // (c0, E0, c1, E1)
    float4 A = awq[ii];
    float wv = wq[ii];
    float x00 = A.x + cv.x, x01 = A.x + cv.z;
    float x10 = A.y + cv.x, x11 = A.y + cv.z;
    float d00 = fmaf(A.z, cv.y, 1.f), d01 = fmaf(A.z, cv.w, 1.f);
    float d10 = fmaf(A.w, cv.y, 1.f), d11 = fmaf(A.w, cv.w, 1.f);
    float mA = d00 * d01, mB = d10 * d11;
    float r = FAST_RCP(mA * mB);
    float rA = r * mB, rB = r * mA;
    acc[0] = fmaf(x00 * wv, rA * d01, acc[0]);
    acc[1] = fmaf(x01 * wv, rA * d00, acc[1]);
    acc[2] = fmaf(x10 * wv, rB * d11, acc[2]);
    acc[3] = fmaf(x11 * wv, rB * d10, acc[3]);
    cb += NL * 2;
  }

  // fold lane bits 4,5 (q-subgroups within wave)
#pragma unroll
  for (int k = 0; k < 4; ++k) {
    acc[k] += __shfl_xor(acc[k], 16, 64);
    acc[k] += __shfl_xor(acc[k], 32, 64);
  }
  if (lane < 16)
    red[w][lane] = make_float4(acc[0], acc[1], acc[2], acc[3]);
  __syncthreads();
  if (tid < 16) {
    float4 v0 = red[0][tid];
    float4 v1 = red[1][tid];
    float4 v2 = red[2][tid];
    float4 v3 = red[3][tid];
    const float bb = b2[0];
    float s0t0 = (v0.x + v1.x) + (v2.x + v3.x) + bb;
    float s0t1 = (v0.y + v1.y) + (v2.y + v3.y) + bb;
    float s1t0 = (v0.z + v1.z) + (v2.z + v3.z) + bb;
    float s1t1 = (v0.w + v1.w) + (v2.w + v3.w) + bb;
    float* o0 = out + 2 * NM + (size_t)s0 * NL + tbase + tid * 2;
    float* o1 = o0 + NL;
    *reinterpret_cast<float2*>(o0) = make_float2(s0t0, s0t1);
    *reinterpret_cast<float2*>(o1) = make_float2(s1t0, s1t1);
  }
}

// ---------------------------------------------------------------------------
extern "C" void kernel_launch(void* const* d_in, const int* in_sizes, int n_in,
                              void* d_out, int out_size, void* d_ws, size_t ws_size,
                              hipStream_t stream) {
  const float* hs = (const float*)d_in[0];
  const float* sw = (const float*)d_in[1];
  const float* sb = (const float*)d_in[2];
  const float* ew = (const float*)d_in[3];
  const float* eb = (const float*)d_in[4];
  const float* w1 = (const float*)d_in[5];
  const float* b1 = (const float*)d_in[6];
  const float* w2 = (const float*)d_in[7];
  const float* b2 = (const float*)d_in[8];
  float* out = (float*)d_out;

  float* a  = (float*)d_ws;                           // M*I floats = 3 MB
  float* cE = (float*)d_ws + (size_t)NM * NI;         // B*I*L*2 floats = 6 MB

  logits_kernel<<<NM, 256, 0, stream>>>(hs, sw, sb, ew, eb, out);

  dim3 ggrid(NM / 64, NI / 96, 2);
  gemm_mfma<<<ggrid, 512, 0, stream>>>(hs, w1, b1, a, cE);

  span_kernel<<<2048, 256, 0, stream>>>(a, cE, w2, b2, out);
}

// Round 17
// 72.554 us; speedup vs baseline: 1.0935x; 1.0533x over previous
//
#include <hip/hip_runtime.h>
#include <math.h>

#define NB 2
#define NL 256
#define NH 768
#define NI 1536
#define NM (NB * NL)   // 512

typedef __attribute__((ext_vector_type(8))) short bf16x8;
typedef __attribute__((ext_vector_type(4))) float f32x4;

#if __has_builtin(__builtin_amdgcn_exp2f)
#define FAST_EXP2(x) __builtin_amdgcn_exp2f(x)
#else
#define FAST_EXP2(x) exp2f(x)
#endif
#if __has_builtin(__builtin_amdgcn_rcpf)
#define FAST_RCP(x) __builtin_amdgcn_rcpf(x)
#else
#define FAST_RCP(x) (1.0f / (x))
#endif

#define KQ (-2.4554669f)   // -1.702 * log2(e)  (quick-gelu exponent)

// fp32 -> bf16 round-to-nearest-even, packed pair
__device__ __forceinline__ unsigned short f2bf(float f) {
  unsigned int u = __builtin_bit_cast(unsigned int, f);
  u += 0x7FFFu + ((u >> 16) & 1u);
  return (unsigned short)(u >> 16);
}
__device__ __forceinline__ unsigned int pack2(float lo, float hi) {
  return (unsigned int)f2bf(lo) | ((unsigned int)f2bf(hi) << 16);
}

// ---------------------------------------------------------------------------
// Kernel 1: start/end logits. One block per row m, 256 threads.
// ---------------------------------------------------------------------------
__global__ __launch_bounds__(256) void logits_kernel(
    const float* __restrict__ hs,
    const float* __restrict__ sw, const float* __restrict__ sb,
    const float* __restrict__ ew, const float* __restrict__ eb,
    float* __restrict__ out) {
  int m = blockIdx.x;
  int tid = threadIdx.x;
  const float* row = hs + (size_t)m * NH;
  float accs = 0.f, acce = 0.f;
  for (int h = tid; h < NH; h += 256) {
    float v = row[h];
    accs = fmaf(v, sw[h], accs);
    acce = fmaf(v, ew[h], acce);
  }
  for (int off = 32; off > 0; off >>= 1) {
    accs += __shfl_down(accs, off, 64);
    acce += __shfl_down(acce, off, 64);
  }
  __shared__ float s_s[4], s_e[4];
  int wid = tid >> 6;
  if ((tid & 63) == 0) { s_s[wid] = accs; s_e[wid] = acce; }
  __syncthreads();
  if (tid == 0) {
    float ts = s_s[0] + s_s[1] + s_s[2] + s_s[3];
    float te = s_e[0] + s_e[1] + s_e[2] + s_e[3];
    out[m]      = ts + sb[0];
    out[NM + m] = te + eb[0];
  }
}

// ---------------------------------------------------------------------------
// Kernel 2: bf16 MFMA GEMM (R13 structure). mode-1 epilogue emits the pair
// (cw, E) = (c * w2[i], exp2(KQ * c)) interleaved: cE[b][i][t] float2.
// mode = blockIdx.z: 0 -> aOut[m][n] (+b1);  1 -> cE interleaved
// ---------------------------------------------------------------------------
__global__ __launch_bounds__(512) void gemm_mfma(
    const float* __restrict__ hs, const float* __restrict__ w1,
    const float* __restrict__ b1, const float* __restrict__ w2,
    float* __restrict__ aOut, float* __restrict__ cE) {
  constexpr int BM = 64, BN = 96, BK = 32;
  __shared__ short A_lds[BM * BK];   // [64][32] swizzled, 4 KB
  __shared__ short B_lds[BN * BK];   // [96][32] swizzled, 6 KB

  const int mode = blockIdx.z;
  const float* __restrict__ W = w1 + (size_t)mode * NH * NI;
  const int m0 = blockIdx.x * BM;
  const int n0 = blockIdx.y * BN;
  const int tid = threadIdx.x;
  const int lane = tid & 63;
  const int wid = tid >> 6;          // 0..7
  const int wr = wid >> 1;           // 0..3  (m quarter, 16 rows)
  const int wc = wid & 1;            // 0..1  (n half, 48 cols)

  const int ar  = tid >> 3;          // A row 0..63
  const int ac  = (tid & 7) * 4;     // A k-offset, float4
  const int bkq = (tid >> 5) * 2;    // B k-offset, 2 rows
  const int bnl = tid & 31;          // B n-lane

  f32x4 acc[3] = {};

  float4 av = *reinterpret_cast<const float4*>(hs + (size_t)(m0 + ar) * NH + ac);
  float bv[2][3];
#pragma unroll
  for (int j = 0; j < 2; ++j) {
    const float* pb = W + (size_t)(bkq + j) * NI + n0 + bnl;
#pragma unroll
    for (int nn = 0; nn < 3; ++nn) bv[j][nn] = pb[nn * 32];
  }

  for (int k0 = 0; k0 < NH; k0 += BK) {
    __syncthreads();
    {
      uint2 v;
      v.x = pack2(av.x, av.y);
      v.y = pack2(av.z, av.w);
      const int off = ar * 64 + ((((ac >> 3) & 3) ^ (ar & 3)) << 4) + ((ac & 4) << 1);
      *reinterpret_cast<uint2*>(reinterpret_cast<char*>(A_lds) + off) = v;
    }
#pragma unroll
    for (int nn = 0; nn < 3; ++nn) {
      const int n = bnl + nn * 32;
      unsigned int v = pack2(bv[0][nn], bv[1][nn]);
      const int off = n * 64 + (((bkq >> 3) ^ (n & 3)) << 4) + ((bkq * 2) & 12);
      *reinterpret_cast<unsigned int*>(reinterpret_cast<char*>(B_lds) + off) = v;
    }
    __syncthreads();
    const int kn = k0 + BK;
    if (kn < NH) {
      av = *reinterpret_cast<const float4*>(hs + (size_t)(m0 + ar) * NH + kn + ac);
#pragma unroll
      for (int j = 0; j < 2; ++j) {
        const float* pb = W + (size_t)(kn + bkq + j) * NI + n0 + bnl;
#pragma unroll
        for (int nn = 0; nn < 3; ++nn) bv[j][nn] = pb[nn * 32];
      }
    }
    const int lr = lane & 15, ls = lane >> 4;
    bf16x8 af, bf[3];
    {
      const int row = wr * 16 + lr;
      const int off = row * 64 + ((ls ^ (row & 3)) << 4);
      af = *reinterpret_cast<const bf16x8*>(reinterpret_cast<const char*>(A_lds) + off);
    }
#pragma unroll
    for (int nt = 0; nt < 3; ++nt) {
      const int nrow = wc * 48 + nt * 16 + lr;
      const int off = nrow * 64 + ((ls ^ (nrow & 3)) << 4);
      bf[nt] = *reinterpret_cast<const bf16x8*>(reinterpret_cast<const char*>(B_lds) + off);
    }
#pragma unroll
    for (int nt = 0; nt < 3; ++nt)
      acc[nt] = __builtin_amdgcn_mfma_f32_16x16x32_bf16(af, bf[nt], acc[nt], 0, 0, 0);
  }

  const int lr = lane & 15, lq = lane >> 4;
  if (mode == 0) {
    const int mb = m0 + wr * 16 + lq * 4;
#pragma unroll
    for (int nt = 0; nt < 3; ++nt) {
      const int n = n0 + wc * 48 + nt * 16 + lr;
      const float bias = b1[n];
#pragma unroll
      for (int r = 0; r < 4; ++r)
        aOut[(size_t)(mb + r) * NI + n] = acc[nt][r] + bias;
    }
  } else {
    // interleaved (c*w2[i], exp2(KQ*c)) per t; acc[nt][r] is t = tb + r
    const int b = m0 >> 8;
    const int tb = (m0 & (NL - 1)) + wr * 16 + lq * 4;
#pragma unroll
    for (int nt = 0; nt < 3; ++nt) {
      const int i = n0 + wc * 48 + nt * 16 + lr;
      const float wv = w2[i];
      float* dst = cE + (((size_t)b * NI + i) * NL + tb) * 2;
      f32x4 v = acc[nt];
      float4 lo = make_float4(v[0] * wv, FAST_EXP2(KQ * v[0]),
                              v[1] * wv, FAST_EXP2(KQ * v[1]));
      float4 hi = make_float4(v[2] * wv, FAST_EXP2(KQ * v[2]),
                              v[3] * wv, FAST_EXP2(KQ * v[3]));
      *reinterpret_cast<float4*>(dst)     = lo;
      *reinterpret_cast<float4*>(dst + 4) = hi;
    }
  }
}

// ---------------------------------------------------------------------------
// Kernel 3: span logits v13 — factorized exp + w2 folded into BOTH operands.
// num = (a+c)*w = a*w + c*w : one add (a*w staged in LDS, c*w in cE).
// d = fma(Ea, Ec, 1); batched rcp per 4 t; acc = fma(num, 1/d, acc).
// Lane covers 8 elems/iter (4 t x 2 s): two adjacent float4 cE loads (32 B
// contiguous), ONE float4 LDS read (a0w, a1w, Ea0, Ea1) — no w read at all.
// 42 VALU + 2 rcp per 8 elems (~14.5 cy/elem). 48 iters.
// Grid 2048 = 256 s-pairs x 8 t-eighths, 256 thr: t8 = tid&7 (8 lanes x 4t),
// q = tid>>3 (32 i-chunks of 48). Reduction = R14's proven shape.
// ---------------------------------------------------------------------------
__global__ __launch_bounds__(256, 2) void span_kernel(
    const float* __restrict__ aRow,   // [M][I], b1 folded
    const float* __restrict__ cE,     // [B][I][L] float2 (c*w2, exp2(KQ*c))
    const float* __restrict__ w2,
    const float* __restrict__ b2,
    float* __restrict__ out) {
  const int blk = blockIdx.x;          // 0..2047
  const int sg  = blk >> 3;            // s-pair 0..255
  const int te  = blk & 7;             // t-eighth
  const int s0  = sg * 2;
  const int b   = s0 >> 8;
  const int tbase = te * 32;
  const int tid = threadIdx.x;
  const int t8  = tid & 7;             // 8 lanes x 4 t = 32 t
  const int q   = tid >> 3;            // 0..31, 48-i chunk each
  const int lane = tid & 63;
  const int w    = tid >> 6;           // wave 0..3

  __shared__ float4 aw4[NI + 32];      // (a0*w, a1*w, Ea0, Ea1), skew i+i/48: 25 KB
  __shared__ float4 red[4][2][8];      // 1 KB

  const float* a0p = aRow + (size_t)s0 * NI;
  const float* a1p = a0p + NI;
  for (int i = tid; i < NI; i += 256) {
    float a0 = a0p[i], a1 = a1p[i], wv = w2[i];
    aw4[i + i / 48] = make_float4(a0 * wv, a1 * wv,
                                  FAST_EXP2(KQ * a0), FAST_EXP2(KQ * a1));
  }
  __syncthreads();

  const float* cb = cE + (((size_t)b * NI + q * 48) * NL + tbase + t8 * 4) * 2;
  const float4* awq = aw4 + q * 49;

  f32x4 acc0 = {0.f, 0.f, 0.f, 0.f};   // s0, t0..3
  f32x4 acc1 = {0.f, 0.f, 0.f, 0.f};   // s1, t0..3

#pragma unroll 4
  for (int ii = 0; ii < 48; ++ii) {
    float4 cv01 = *reinterpret_cast<const float4*>(cb);       // (cw0,E0,cw1,E1)
    float4 cv23 = *reinterpret_cast<const float4*>(cb + 4);   // (cw2,E2,cw3,E3)
    float4 A = awq[ii];                 // (a0w, a1w, Ea0, Ea1)
    // s = 0
    {
      float n0 = A.x + cv01.x, n1 = A.x + cv01.z;
      float n2 = A.x + cv23.x, n3 = A.x + cv23.z;
      float d0 = fmaf(A.z, cv01.y, 1.f), d1 = fmaf(A.z, cv01.w, 1.f);
      float d2 = fmaf(A.z, cv23.y, 1.f), d3 = fmaf(A.z, cv23.w, 1.f);
      float mA = d0 * d1, mB = d2 * d3;
      float r = FAST_RCP(mA * mB);
      float rA = r * mB, rB = r * mA;
      acc0[0] = fmaf(n0, rA * d1, acc0[0]);
      acc0[1] = fmaf(n1, rA * d0, acc0[1]);
      acc0[2] = fmaf(n2, rB * d3, acc0[2]);
      acc0[3] = fmaf(n3, rB * d2, acc0[3]);
    }
    // s = 1
    {
      float n0 = A.y + cv01.x, n1 = A.y + cv01.z;
      float n2 = A.y + cv23.x, n3 = A.y + cv23.z;
      float d0 = fmaf(A.w, cv01.y, 1.f), d1 = fmaf(A.w, cv01.w, 1.f);
      float d2 = fmaf(A.w, cv23.y, 1.f), d3 = fmaf(A.w, cv23.w, 1.f);
      float mA = d0 * d1, mB = d2 * d3;
      float r = FAST_RCP(mA * mB);
      float rA = r * mB, rB = r * mA;
      acc1[0] = fmaf(n0, rA * d1, acc1[0]);
      acc1[1] = fmaf(n1, rA * d0, acc1[1]);
      acc1[2] = fmaf(n2, rB * d3, acc1[2]);
      acc1[3] = fmaf(n3, rB * d2, acc1[3]);
    }
    cb += NL * 2;
  }

  // fold lane bits 3,4,5 (q-subgroups within wave)
#pragma unroll
  for (int k = 0; k < 4; ++k) {
    acc0[k] += __shfl_xor(acc0[k], 8, 64);
    acc0[k] += __shfl_xor(acc0[k], 16, 64);
    acc0[k] += __shfl_xor(acc0[k], 32, 64);
    acc1[k] += __shfl_xor(acc1[k], 8, 64);
    acc1[k] += __shfl_xor(acc1[k], 16, 64);
    acc1[k] += __shfl_xor(acc1[k], 32, 64);
  }
  if (lane < 8) {
    red[w][0][lane] = make_float4(acc0[0], acc0[1], acc0[2], acc0[3]);
    red[w][1][lane] = make_float4(acc1[0], acc1[1], acc1[2], acc1[3]);
  }
  __syncthreads();
  if (tid < 16) {
    const int s = tid >> 3;
    const int tt = tid & 7;
    float4 v0 = red[0][s][tt];
    float4 v1 = red[1][s][tt];
    float4 v2 = red[2][s][tt];
    float4 v3 = red[3][s][tt];
    const float bb = b2[0];
    float4 o;
    o.x = (v0.x + v1.x) + (v2.x + v3.x) + bb;
    o.y = (v0.y + v1.y) + (v2.y + v3.y) + bb;
    o.z = (v0.z + v1.z) + (v2.z + v3.z) + bb;
    o.w = (v0.w + v1.w) + (v2.w + v3.w) + bb;
    *reinterpret_cast<float4*>(out + 2 * NM + (size_t)(s0 + s) * NL + tbase + tt * 4) = o;
  }
}

// ---------------------------------------------------------------------------
extern "C" void kernel_launch(void* const* d_in, const int* in_sizes, int n_in,
                              void* d_out, int out_size, void* d_ws, size_t ws_size,
                              hipStream_t stream) {
  const float* hs = (const float*)d_in[0];
  const float* sw = (const float*)d_in[1];
  const float* sb = (const float*)d_in[2];
  const float* ew = (const float*)d_in[3];
  const float* eb = (const float*)d_in[4];
  const float* w1 = (const float*)d_in[5];
  const float* b1 = (const float*)d_in[6];
  const float* w2 = (const float*)d_in[7];
  const float* b2 = (const float*)d_in[8];
  float* out = (float*)d_out;

  float* a  = (float*)d_ws;                           // M*I floats = 3 MB
  float* cE = (float*)d_ws + (size_t)NM * NI;         // B*I*L*2 floats = 6 MB

  logits_kernel<<<NM, 256, 0, stream>>>(hs, sw, sb, ew, eb, out);

  dim3 ggrid(NM / 64, NI / 96, 2);
  gemm_mfma<<<ggrid, 512, 0, stream>>>(hs, w1, b1, w2, a, cE);

  span_kernel<<<2048, 256, 0, stream>>>(a, cE, w2, b2, out);
}

// Round 18
// 61.897 us; speedup vs baseline: 1.2817x; 1.1722x over previous
//
#include <hip/hip_runtime.h>
#include <math.h>

#define NB 2
#define NL 256
#define NH 768
#define NI 1536
#define NM (NB * NL)   // 512

typedef __attribute__((ext_vector_type(8))) short bf16x8;
typedef __attribute__((ext_vector_type(4))) float f32x4;
typedef __attribute__((ext_vector_type(4))) unsigned int u32x4;

#if __has_builtin(__builtin_amdgcn_exp2f)
#define FAST_EXP2(x) __builtin_amdgcn_exp2f(x)
#else
#define FAST_EXP2(x) exp2f(x)
#endif
#if __has_builtin(__builtin_amdgcn_rcpf)
#define FAST_RCP(x) __builtin_amdgcn_rcpf(x)
#else
#define FAST_RCP(x) (1.0f / (x))
#endif

#define KQ (-2.4554669f)   // -1.702 * log2(e)  (quick-gelu exponent)

// fp32 -> bf16 round-to-nearest-even, packed pair (lo in low 16, hi in high 16)
__device__ __forceinline__ unsigned short f2bf(float f) {
  unsigned int u = __builtin_bit_cast(unsigned int, f);
  u += 0x7FFFu + ((u >> 16) & 1u);
  return (unsigned short)(u >> 16);
}
__device__ __forceinline__ unsigned int pack2(float lo, float hi) {
  return (unsigned int)f2bf(lo) | ((unsigned int)f2bf(hi) << 16);
}
__device__ __forceinline__ float bits2f(unsigned int u) {
  return __builtin_bit_cast(float, u);
}

// ---------------------------------------------------------------------------
// Kernel 2+1 fused: bf16 MFMA GEMM (z=0,1) + start/end logits (z=2).
// z=0: aOut[m][n] = hs @ w1[:H] + b1
// z=1: cE[b][i][t] = u32( bf16(c*w2[i]) | bf16(exp2(KQ*c))<<16 )
// z=2: 128 blocks x 512 thr, 4 rows each -> start/end logits.
// ---------------------------------------------------------------------------
__global__ __launch_bounds__(512) void gemm_mfma(
    const float* __restrict__ hs, const float* __restrict__ w1,
    const float* __restrict__ b1, const float* __restrict__ w2,
    const float* __restrict__ sw, const float* __restrict__ sb,
    const float* __restrict__ ew, const float* __restrict__ eb,
    float* __restrict__ aOut, unsigned int* __restrict__ cE,
    float* __restrict__ out) {
  constexpr int BM = 64, BN = 96, BK = 32;
  __shared__ short A_lds[BM * BK];   // [64][32] swizzled, 4 KB
  __shared__ short B_lds[BN * BK];   // [96][32] swizzled, 6 KB
  __shared__ float ls_s[4][2], ls_e[4][2];

  const int tid = threadIdx.x;

  if (blockIdx.z == 2) {
    // ---- logits slice: gid in 0..127, 4 rows per block, 128 thr per row
    const int gid = blockIdx.x * 16 + blockIdx.y;
    const int g = tid >> 7;          // row group 0..3
    const int l = tid & 127;
    const int m = gid * 4 + g;
    const float* row = hs + (size_t)m * NH;
    float accs = 0.f, acce = 0.f;
    for (int h = l; h < NH; h += 128) {
      float v = row[h];
      accs = fmaf(v, sw[h], accs);
      acce = fmaf(v, ew[h], acce);
    }
    for (int off = 32; off > 0; off >>= 1) {
      accs += __shfl_down(accs, off, 64);
      acce += __shfl_down(acce, off, 64);
    }
    if ((tid & 63) == 0) {
      ls_s[g][(tid >> 6) & 1] = accs;
      ls_e[g][(tid >> 6) & 1] = acce;
    }
    __syncthreads();
    if (l == 0) {
      out[m]      = ls_s[g][0] + ls_s[g][1] + sb[0];
      out[NM + m] = ls_e[g][0] + ls_e[g][1] + eb[0];
    }
    return;
  }

  const int mode = blockIdx.z;
  const float* __restrict__ W = w1 + (size_t)mode * NH * NI;
  const int m0 = blockIdx.x * BM;
  const int n0 = blockIdx.y * BN;
  const int lane = tid & 63;
  const int wid = tid >> 6;          // 0..7
  const int wr = wid >> 1;           // 0..3  (m quarter, 16 rows)
  const int wc = wid & 1;            // 0..1  (n half, 48 cols)

  const int ar  = tid >> 3;          // A row 0..63
  const int ac  = (tid & 7) * 4;     // A k-offset, float4
  const int bkq = (tid >> 5) * 2;    // B k-offset, 2 rows
  const int bnl = tid & 31;          // B n-lane

  f32x4 acc[3] = {};

  float4 av = *reinterpret_cast<const float4*>(hs + (size_t)(m0 + ar) * NH + ac);
  float bv[2][3];
#pragma unroll
  for (int j = 0; j < 2; ++j) {
    const float* pb = W + (size_t)(bkq + j) * NI + n0 + bnl;
#pragma unroll
    for (int nn = 0; nn < 3; ++nn) bv[j][nn] = pb[nn * 32];
  }

  for (int k0 = 0; k0 < NH; k0 += BK) {
    __syncthreads();
    {
      uint2 v;
      v.x = pack2(av.x, av.y);
      v.y = pack2(av.z, av.w);
      const int off = ar * 64 + ((((ac >> 3) & 3) ^ (ar & 3)) << 4) + ((ac & 4) << 1);
      *reinterpret_cast<uint2*>(reinterpret_cast<char*>(A_lds) + off) = v;
    }
#pragma unroll
    for (int nn = 0; nn < 3; ++nn) {
      const int n = bnl + nn * 32;
      unsigned int v = pack2(bv[0][nn], bv[1][nn]);
      const int off = n * 64 + (((bkq >> 3) ^ (n & 3)) << 4) + ((bkq * 2) & 12);
      *reinterpret_cast<unsigned int*>(reinterpret_cast<char*>(B_lds) + off) = v;
    }
    __syncthreads();
    const int kn = k0 + BK;
    if (kn < NH) {
      av = *reinterpret_cast<const float4*>(hs + (size_t)(m0 + ar) * NH + kn + ac);
#pragma unroll
      for (int j = 0; j < 2; ++j) {
        const float* pb = W + (size_t)(kn + bkq + j) * NI + n0 + bnl;
#pragma unroll
        for (int nn = 0; nn < 3; ++nn) bv[j][nn] = pb[nn * 32];
      }
    }
    const int lr = lane & 15, ls = lane >> 4;
    bf16x8 af, bf[3];
    {
      const int row = wr * 16 + lr;
      const int off = row * 64 + ((ls ^ (row & 3)) << 4);
      af = *reinterpret_cast<const bf16x8*>(reinterpret_cast<const char*>(A_lds) + off);
    }
#pragma unroll
    for (int nt = 0; nt < 3; ++nt) {
      const int nrow = wc * 48 + nt * 16 + lr;
      const int off = nrow * 64 + ((ls ^ (nrow & 3)) << 4);
      bf[nt] = *reinterpret_cast<const bf16x8*>(reinterpret_cast<const char*>(B_lds) + off);
    }
#pragma unroll
    for (int nt = 0; nt < 3; ++nt)
      acc[nt] = __builtin_amdgcn_mfma_f32_16x16x32_bf16(af, bf[nt], acc[nt], 0, 0, 0);
  }

  const int lr = lane & 15, lq = lane >> 4;
  if (mode == 0) {
    const int mb = m0 + wr * 16 + lq * 4;
#pragma unroll
    for (int nt = 0; nt < 3; ++nt) {
      const int n = n0 + wc * 48 + nt * 16 + lr;
      const float bias = b1[n];
#pragma unroll
      for (int r = 0; r < 4; ++r)
        aOut[(size_t)(mb + r) * NI + n] = acc[nt][r] + bias;
    }
  } else {
    // packed (bf16(c*w2) | bf16(exp2(KQ*c))<<16) per t; acc[nt][r] is t = tb+r
    const int b = m0 >> 8;
    const int tb = (m0 & (NL - 1)) + wr * 16 + lq * 4;
#pragma unroll
    for (int nt = 0; nt < 3; ++nt) {
      const int i = n0 + wc * 48 + nt * 16 + lr;
      const float wv = w2[i];
      unsigned int* dst = cE + ((size_t)b * NI + i) * NL + tb;
      f32x4 v = acc[nt];
      u32x4 pk;
      pk.x = pack2(v[0] * wv, FAST_EXP2(KQ * v[0]));
      pk.y = pack2(v[1] * wv, FAST_EXP2(KQ * v[1]));
      pk.z = pack2(v[2] * wv, FAST_EXP2(KQ * v[2]));
      pk.w = pack2(v[3] * wv, FAST_EXP2(KQ * v[3]));
      *reinterpret_cast<u32x4*>(dst) = pk;
    }
  }
}

// ---------------------------------------------------------------------------
// Kernel 3: span logits v14 — factorized exp, w2 folded, bf16-PACKED cE.
// Each cE element = u32(bf16(cw) | bf16(Ec)<<16): unpack = u<<16 / u&hi16.
// Per iter: 8 elems (4 t x 2 s) = ONE uint4 global load + ONE float4 LDS
// read + 48 VALU + 2 rcp. Half the L2 traffic of R17 (402 MB).
// Grid 2048 = 256 s-pairs x 8 t-eighths, 256 thr: t8 = tid&7, q = tid>>3.
// ---------------------------------------------------------------------------
__global__ __launch_bounds__(256, 2) void span_kernel(
    const float* __restrict__ aRow,   // [M][I], b1 folded
    const unsigned int* __restrict__ cE,  // [B][I][L] packed
    const float* __restrict__ w2,
    const float* __restrict__ b2,
    float* __restrict__ out) {
  const int blk = blockIdx.x;          // 0..2047
  const int sg  = blk >> 3;            // s-pair 0..255
  const int te  = blk & 7;             // t-eighth
  const int s0  = sg * 2;
  const int b   = s0 >> 8;
  const int tbase = te * 32;
  const int tid = threadIdx.x;
  const int t8  = tid & 7;             // 8 lanes x 4 t = 32 t
  const int q   = tid >> 3;            // 0..31, 48-i chunk each
  const int lane = tid & 63;
  const int w    = tid >> 6;           // wave 0..3

  __shared__ float4 aw4[NI + 32];      // (a0*w, a1*w, Ea0, Ea1), skew i+i/48: 25 KB
  __shared__ float4 red[4][2][8];      // 1 KB

  const float* a0p = aRow + (size_t)s0 * NI;
  const float* a1p = a0p + NI;
  for (int i = tid; i < NI; i += 256) {
    float a0 = a0p[i], a1 = a1p[i], wv = w2[i];
    aw4[i + i / 48] = make_float4(a0 * wv, a1 * wv,
                                  FAST_EXP2(KQ * a0), FAST_EXP2(KQ * a1));
  }
  __syncthreads();

  const unsigned int* cb = cE + ((size_t)b * NI + q * 48) * NL + tbase + t8 * 4;
  const float4* awq = aw4 + q * 49;

  f32x4 acc0 = {0.f, 0.f, 0.f, 0.f};   // s0, t0..3
  f32x4 acc1 = {0.f, 0.f, 0.f, 0.f};   // s1, t0..3

#pragma unroll 4
  for (int ii = 0; ii < 48; ++ii) {
    u32x4 cv = *reinterpret_cast<const u32x4*>(cb);   // 4 packed (cw,E)
    float4 A = awq[ii];                 // (a0w, a1w, Ea0, Ea1)
    float cw0 = bits2f(cv.x << 16), E0 = bits2f(cv.x & 0xFFFF0000u);
    float cw1 = bits2f(cv.y << 16), E1 = bits2f(cv.y & 0xFFFF0000u);
    float cw2 = bits2f(cv.z << 16), E2 = bits2f(cv.z & 0xFFFF0000u);
    float cw3 = bits2f(cv.w << 16), E3 = bits2f(cv.w & 0xFFFF0000u);
    // s = 0
    {
      float n0 = A.x + cw0, n1 = A.x + cw1;
      float n2 = A.x + cw2, n3 = A.x + cw3;
      float d0 = fmaf(A.z, E0, 1.f), d1 = fmaf(A.z, E1, 1.f);
      float d2 = fmaf(A.z, E2, 1.f), d3 = fmaf(A.z, E3, 1.f);
      float mA = d0 * d1, mB = d2 * d3;
      float r = FAST_RCP(mA * mB);
      float rA = r * mB, rB = r * mA;
      acc0[0] = fmaf(n0, rA * d1, acc0[0]);
      acc0[1] = fmaf(n1, rA * d0, acc0[1]);
      acc0[2] = fmaf(n2, rB * d3, acc0[2]);
      acc0[3] = fmaf(n3, rB * d2, acc0[3]);
    }
    // s = 1
    {
      float n0 = A.y + cw0, n1 = A.y + cw1;
      float n2 = A.y + cw2, n3 = A.y + cw3;
      float d0 = fmaf(A.w, E0, 1.f), d1 = fmaf(A.w, E1, 1.f);
      float d2 = fmaf(A.w, E2, 1.f), d3 = fmaf(A.w, E3, 1.f);
      float mA = d0 * d1, mB = d2 * d3;
      float r = FAST_RCP(mA * mB);
      float rA = r * mB, rB = r * mA;
      acc1[0] = fmaf(n0, rA * d1, acc1[0]);
      acc1[1] = fmaf(n1, rA * d0, acc1[1]);
      acc1[2] = fmaf(n2, rB * d3, acc1[2]);
      acc1[3] = fmaf(n3, rB * d2, acc1[3]);
    }
    cb += NL;
  }

  // fold lane bits 3,4,5 (q-subgroups within wave)
#pragma unroll
  for (int k = 0; k < 4; ++k) {
    acc0[k] += __shfl_xor(acc0[k], 8, 64);
    acc0[k] += __shfl_xor(acc0[k], 16, 64);
    acc0[k] += __shfl_xor(acc0[k], 32, 64);
    acc1[k] += __shfl_xor(acc1[k], 8, 64);
    acc1[k] += __shfl_xor(acc1[k], 16, 64);
    acc1[k] += __shfl_xor(acc1[k], 32, 64);
  }
  if (lane < 8) {
    red[w][0][lane] = make_float4(acc0[0], acc0[1], acc0[2], acc0[3]);
    red[w][1][lane] = make_float4(acc1[0], acc1[1], acc1[2], acc1[3]);
  }
  __syncthreads();
  if (tid < 16) {
    const int s = tid >> 3;
    const int tt = tid & 7;
    float4 v0 = red[0][s][tt];
    float4 v1 = red[1][s][tt];
    float4 v2 = red[2][s][tt];
    float4 v3 = red[3][s][tt];
    const float bb = b2[0];
    float4 o;
    o.x = (v0.x + v1.x) + (v2.x + v3.x) + bb;
    o.y = (v0.y + v1.y) + (v2.y + v3.y) + bb;
    o.z = (v0.z + v1.z) + (v2.z + v3.z) + bb;
    o.w = (v0.w + v1.w) + (v2.w + v3.w) + bb;
    *reinterpret_cast<float4*>(out + 2 * NM + (size_t)(s0 + s) * NL + tbase + tt * 4) = o;
  }
}

// ---------------------------------------------------------------------------
extern "C" void kernel_launch(void* const* d_in, const int* in_sizes, int n_in,
                              void* d_out, int out_size, void* d_ws, size_t ws_size,
                              hipStream_t stream) {
  const float* hs = (const float*)d_in[0];
  const float* sw = (const float*)d_in[1];
  const float* sb = (const float*)d_in[2];
  const float* ew = (const float*)d_in[3];
  const float* eb = (const float*)d_in[4];
  const float* w1 = (const float*)d_in[5];
  const float* b1 = (const float*)d_in[6];
  const float* w2 = (const float*)d_in[7];
  const float* b2 = (const float*)d_in[8];
  float* out = (float*)d_out;

  float* a = (float*)d_ws;                                      // M*I f32 = 3 MB
  unsigned int* cE = (unsigned int*)((float*)d_ws + (size_t)NM * NI);  // 3 MB

  dim3 ggrid(NM / 64, NI / 96, 3);   // z=0: a, z=1: cE, z=2: logits
  gemm_mfma<<<ggrid, 512, 0, stream>>>(hs, w1, b1, w2, sw, sb, ew, eb, a, cE, out);

  span_kernel<<<2048, 256, 0, stream>>>(a, cE, w2, b2, out);
}